// Round 1
// baseline (176.884 us; speedup 1.0000x reference)
//
#include <hip/hip_runtime.h>
#include <cstdint>

#define NB 64
#define NC 256
#define ND 256
#define NT 4096

#define BT 64                    // t-columns per tile
#define NTILES 16                // tiles per block
#define CHUNK (BT * NTILES)      // 1024 t per block
#define NCHUNK (NT / CHUNK)      // 4 chunks

typedef __attribute__((ext_vector_type(8)))  _Float16 half8;
typedef __attribute__((ext_vector_type(16))) float    f32x16;

union Frag {
    uint32_t u[4];
    half8    v;
};

__device__ __forceinline__ uint32_t pk_f16(float lo, float hi) {
    // v_cvt_pkrtz_f16_f32: D.lo = f16(lo), D.hi = f16(hi)  (matches MFMA k, k+1 packing)
    return __builtin_bit_cast(uint32_t, __builtin_amdgcn_cvt_pkrtz(lo, hi));
}

__global__ __launch_bounds__(512, 2)
void subject_gemm(const float* __restrict__ x,
                  const int*   __restrict__ subjects,
                  const float* __restrict__ w,
                  float*       __restrict__ out)
{
    // double-buffered fp32 x-tile: 2 * 256 * 64 * 4B = 128 KiB
    __shared__ float lds[2][NC][BT];

    const int tid  = threadIdx.x;
    const int lane = tid & 63;
    const int wv   = tid >> 6;       // wave 0..7, owns d in [wv*32, wv*32+32)
    const int g    = lane >> 5;      // half-wave: k-group for MFMA operands
    const int l31  = lane & 31;
    const int b    = blockIdx.y;
    const int t0   = blockIdx.x * CHUNK;

    const int sub = subjects[b];
    const float* __restrict__ wsub = w + (size_t)sub * NC * ND;
    const float* __restrict__ xb   = x + (size_t)b * NC * NT;
    float*       __restrict__ ob   = out + (size_t)b * ND * NT;

    const int dlane = wv * 32 + l31;

    // ---- one-time: W B-operand fragments into registers ----
    // B[k][n] layout for mfma_f32_32x32x16: n = lane&31, k = 8*(lane>>5) + j, j=0..7
    Frag wf[16];
#pragma unroll
    for (int ks = 0; ks < 16; ++ks) {
        float f[8];
#pragma unroll
        for (int j = 0; j < 8; ++j)
            f[j] = wsub[(size_t)(ks * 16 + g * 8 + j) * ND + dlane];
#pragma unroll
        for (int p = 0; p < 4; ++p)
            wf[ks].u[p] = pk_f16(f[2 * p], f[2 * p + 1]);
    }

    // ---- staging: 64 x 1KiB global_load_lds per tile (8 per wave) ----
    // instr (wv,i): LDS rows c = (wv*8+i)*4 .. +3, lane L writes 16B at row c+(L>>4), col (L&15)*4
    // global src per lane mirrors that layout exactly (linear LDS dest, rule #21).
    const int crow = (lane >> 4);          // 0..3
    const int tcol = (lane & 15) * 4;      // 0..60

    // prologue: stage tile 0 into buf 0
#pragma unroll
    for (int i = 0; i < 8; ++i) {
        const int seg = wv * 8 + i;
        const float* src = xb + (size_t)(seg * 4 + crow) * NT + (t0 + tcol);
        __builtin_amdgcn_global_load_lds(
            (const __attribute__((address_space(1))) void*)src,
            (__attribute__((address_space(3))) void*)&lds[0][seg * 4][0],
            16, 0, 0);
    }
    __syncthreads();

    for (int tile = 0; tile < NTILES; ++tile) {
        const int buf = tile & 1;

        // issue next tile's loads early (overlap with compute; drained at barrier)
        if (tile + 1 < NTILES) {
            const int tb = t0 + (tile + 1) * BT;
#pragma unroll
            for (int i = 0; i < 8; ++i) {
                const int seg = wv * 8 + i;
                const float* src = xb + (size_t)(seg * 4 + crow) * NT + (tb + tcol);
                __builtin_amdgcn_global_load_lds(
                    (const __attribute__((address_space(1))) void*)src,
                    (__attribute__((address_space(3))) void*)&lds[buf ^ 1][seg * 4][0],
                    16, 0, 0);
            }
        }

        // ---- compute: out-tile (64 t) x (32 d) per wave ----
        f32x16 acc[2] = {};
#pragma unroll
        for (int ks = 0; ks < 16; ++ks) {
#pragma unroll
            for (int m = 0; m < 2; ++m) {
                // A[mrow][k] layout: mrow = lane&31 (=t), k = 8*(lane>>5)+j, j=0..7
                Frag a;
#pragma unroll
                for (int p = 0; p < 4; ++p) {
                    const float lo = lds[buf][ks * 16 + g * 8 + 2 * p    ][m * 32 + l31];
                    const float hi = lds[buf][ks * 16 + g * 8 + 2 * p + 1][m * 32 + l31];
                    a.u[p] = pk_f16(lo, hi);
                }
                acc[m] = __builtin_amdgcn_mfma_f32_32x32x16_f16(a.v, wf[ks].v, acc[m], 0, 0, 0);
            }
        }

        __syncthreads();   // staged tile+1 complete; all waves done reading buf

        // ---- store after barrier: drains at NEXT tile's barrier (hidden) ----
        // C/D layout: col = lane&31 = d ; row = (reg&3) + 8*(reg>>2) + 4*(lane>>5) = t
        const int tb = t0 + tile * BT;
#pragma unroll
        for (int m = 0; m < 2; ++m) {
#pragma unroll
            for (int rg = 0; rg < 4; ++rg) {
                const int trow = tb + m * 32 + rg * 8 + g * 4;
                float4 vv = make_float4(acc[m][4 * rg + 0], acc[m][4 * rg + 1],
                                        acc[m][4 * rg + 2], acc[m][4 * rg + 3]);
                *reinterpret_cast<float4*>(&ob[(size_t)dlane * NT + trow]) = vv;
            }
        }
    }
}

extern "C" void kernel_launch(void* const* d_in, const int* in_sizes, int n_in,
                              void* d_out, int out_size, void* d_ws, size_t ws_size,
                              hipStream_t stream)
{
    const float* x        = (const float*)d_in[0];
    const int*   subjects = (const int*)d_in[1];
    const float* w        = (const float*)d_in[2];
    float*       out      = (float*)d_out;

    dim3 grid(NCHUNK, NB);   // 4 x 64 = 256 blocks = 1 per CU (128 KiB LDS each)
    subject_gemm<<<grid, 512, 0, stream>>>(x, subjects, w, out);
}